// Round 1
// baseline (747.823 us; speedup 1.0000x reference)
//
#include <hip/hip_runtime.h>

#define M    8192
#define MAXN 16
#define TB   256

// ---- ws layout (float offsets) ----
#define WS_S    0            // S_hat state
#define WS_N    1            // int N (bitcast)
#define WS_H    2            // (float)h
#define WS_H2   3            // (float)(0.5*h)
#define WS_H6   4            // (float)(h/6)
#define WS_NST  8            // n state [M]
#define WS_NTMP (WS_NST + M) // n_tmp   [M]
#define WS_V    (WS_NTMP + M)// v = G*n_tmp [M]
#define WS_G    (WS_V + M)   // G [M]
#define WS_GAIN (WS_G + M)   // gain accumulator [M]
#define WS_UP   (WS_GAIN + M)// uptake partials [32]

// ---------------- init: copy n, compute N/h/S (mirrors _num_substeps in f64) -------------
__global__ void k_init(const float* __restrict__ x, const float* __restrict__ m,
                       float* __restrict__ ws) {
  int j = blockIdx.x * TB + threadIdx.x;
  if (j < M) ws[WS_NST + j] = x[j];
  if (blockIdx.x == 0 && threadIdx.x == 0) {
    double S_hat = (double)x[M];
    double S = 10.0 * S_hat;
    double alpha = 0.8 * S / (2.0 + S + 1e-12);
    double mmax = (double)m[M - 1];               // m is ascending
    double vmax = fabs(alpha) * mmax;
    double dm = 0.9 / 8192.0;
    double cfl = vmax * 0.002 / (dm + 1e-12);
    int Ncfl = (vmax == 0.0 || cfl <= 0.8) ? 1 : (int)ceil(cfl / 0.8);
    double rgv = 0.8 * S / (2.0 + S + 1e-12) * mmax;
    double gam = 1.0 / (1.0 - mmax + 1e-12) - 1.0 / (1.0 - 0.45 + 1e-12);
    if (gam < 0.0) gam = 0.0;
    double rate = gam * rgv;                      // G is max at largest m
    int Nre = (rate == 0.0 || rate * 0.002 <= 0.5) ? 1 : (int)ceil(rate * 0.002 / 0.5);
    int N = Ncfl > Nre ? Ncfl : Nre;
    if (N < 1) N = 1;
    if (N > MAXN) N = MAXN;                       // safety; true bound is 14
    double h = 0.002 / (double)N;
    ws[WS_S] = x[M];
    ((int*)ws)[WS_N] = N;
    ws[WS_H]  = (float)h;
    ws[WS_H2] = (float)(0.5 * h);
    ws[WS_H6] = (float)(h / 6.0);
  }
}

// ---------------- per-substep: RK4 stencil + G/v/uptake + zero gain -------------
__global__ __launch_bounds__(TB) void k_stage(const float* __restrict__ m,
                                              float* __restrict__ ws, int step) {
  if (((const int*)ws)[WS_N] <= step) return;
  __shared__ float sn[TB + 4], sm_[TB + 4], ka[TB + 4], kb[TB + 4];
  __shared__ float red[4];
  const int tid  = threadIdx.x;
  const int base = blockIdx.x * TB;
  const float S32   = 10.0f * ws[WS_S];
  const float alpha = 0.8f * S32 / (2.0f + S32);           // transport (no eps)
  const float beta  = 0.8f * S32 / (2.0f + S32 + 1e-12f);  // rg coefficient
  const float hh = ws[WS_H], h2 = ws[WS_H2], h6 = ws[WS_H6];
  const float DM = (float)(0.9 / 8192.0);
  const float C2 = (float)(1.0 / ((1.0 - 0.45) + 1e-12));

  for (int t = tid; t < TB + 4; t += TB) {
    int g = base - 4 + t;
    sn[t]  = (g >= 0) ? ws[WS_NST + g] : 0.0f;
    sm_[t] = (g >= 0) ? m[g] : 0.0f;
    ka[t] = 0.0f; kb[t] = 0.0f;
  }
  __syncthreads();

  // stage: kout = L(sn + c*kprev), valid for t in [1, TB+4)
  auto stage = [&](const float* kprev, float c, float* kout) {
    for (int t = 1 + tid; t < TB + 4; t += TB) {
      int g = base - 4 + t;
      float ng    = sn[t]     + c * kprev[t];
      float nprev = sn[t - 1] + c * kprev[t - 1];
      float rgg = (alpha * sm_[t])     * ng;
      float rgp = (alpha * sm_[t - 1]) * nprev;
      float val;
      if (g == 0)          val = -(rgg / DM);
      else if (g == M - 1) val = rgp / DM + rgg / DM;   // -d[-1] + flux_out/DM
      else                 val = -((rgg - rgp) / DM);
      kout[t] = val;
    }
  };

  stage(kb, 0.0f, ka); __syncthreads();   // k1 -> ka  (kb is zeros)
  float k1o = ka[tid + 4];
  stage(ka, h2, kb);   __syncthreads();   // k2 -> kb
  float k2o = kb[tid + 4];
  stage(kb, h2, ka);   __syncthreads();   // k3 -> ka
  float k3o = ka[tid + 4];
  stage(ka, hh, kb);   __syncthreads();   // k4 -> kb
  float k4o = kb[tid + 4];

  const int g = base + tid;
  float ntmp = sn[tid + 4] + h6 * (k1o + 2.0f * k2o + 2.0f * k3o + k4o);

  float mg  = sm_[tid + 4];
  float rg  = beta * mg;
  float gam = 1.0f / ((1.0f - mg) + 1e-12f) - C2;
  gam = fmaxf(gam, 0.0f);
  float G = gam * rg;
  ws[WS_NTMP + g] = ntmp;
  ws[WS_G + g]    = G;
  ws[WS_V + g]    = G * ntmp;
  ws[WS_GAIN + g] = 0.0f;               // zero accumulator for k_gemv atomics

  // uptake partial: sum(rg * n_tmp) over this block
  float u = rg * ntmp;
  #pragma unroll
  for (int off = 32; off > 0; off >>= 1) u += __shfl_down(u, off, 64);
  if ((tid & 63) == 0) red[tid >> 6] = u;
  __syncthreads();
  if (tid == 0) ws[WS_UP + blockIdx.x] = (red[0] + red[1]) + (red[2] + red[3]);
}

// ---------------- per-substep: gain += v @ P  (split-K, float4 coalesced) -------------
#define KC   64
#define ROWS (M / KC)   // 128
__global__ __launch_bounds__(TB) void k_gemv(const float* __restrict__ P,
                                             float* __restrict__ ws, int step) {
  if (((const int*)ws)[WS_N] <= step) return;
  __shared__ float sv[ROWS];
  const int tid   = threadIdx.x;
  const int chunk = blockIdx.x & (KC - 1);
  const int jt    = blockIdx.x >> 6;           // 0..7
  const int i0    = chunk * ROWS;
  const int j     = jt * (TB * 4) + tid * 4;
  if (tid < ROWS) sv[tid] = ws[WS_V + i0 + tid];
  __syncthreads();
  const float4* __restrict__ Pp = (const float4*)(P + (size_t)i0 * M + j);
  float4 acc = make_float4(0.f, 0.f, 0.f, 0.f);
  #pragma unroll 8
  for (int i = 0; i < ROWS; ++i) {
    float4 p = Pp[(size_t)i * (M / 4)];
    float vi = sv[i];
    acc.x = fmaf(vi, p.x, acc.x);
    acc.y = fmaf(vi, p.y, acc.y);
    acc.z = fmaf(vi, p.z, acc.z);
    acc.w = fmaf(vi, p.w, acc.w);
  }
  atomicAdd(&ws[WS_GAIN + j + 0], acc.x);
  atomicAdd(&ws[WS_GAIN + j + 1], acc.y);
  atomicAdd(&ws[WS_GAIN + j + 2], acc.z);
  atomicAdd(&ws[WS_GAIN + j + 3], acc.w);
}

// ---------------- per-substep: epilogue (n_next, S_next) -------------
__global__ __launch_bounds__(TB) void k_epi(float* __restrict__ ws, int step) {
  if (((const int*)ws)[WS_N] <= step) return;
  const int j = blockIdx.x * TB + threadIdx.x;
  const float hh = ws[WS_H];
  const float TWODM = (float)(2.0 * (0.9 / 8192.0));
  float ntmp  = ws[WS_NTMP + j];
  float G     = ws[WS_G + j];
  float gain  = TWODM * ws[WS_GAIN + j];
  float denom = 1.0f + hh * G;
  float nn    = (ntmp + hh * gain) / denom;
  ws[WS_NST + j] = fmaxf(nn, 0.0f);
  if (blockIdx.x == 0 && threadIdx.x == 0) {
    float up = 0.0f;
    for (int b = 0; b < 32; ++b) up += ws[WS_UP + b];
    up *= (float)(0.9 / 8192.0);                 // * DELTA_M
    float S  = ws[WS_S];
    float Sn = S + hh * (-0.1f * up);            // KAPPA = 0.1
    ws[WS_S] = fmaxf(Sn, 0.0f);
  }
}

// ---------------- final: state -> d_out -------------
__global__ void k_out(const float* __restrict__ ws, float* __restrict__ out) {
  int j = blockIdx.x * TB + threadIdx.x;
  if (j < M) out[j] = ws[WS_NST + j];
  if (j == M) out[M] = ws[WS_S];
}

extern "C" void kernel_launch(void* const* d_in, const int* in_sizes, int n_in,
                              void* d_out, int out_size, void* d_ws, size_t ws_size,
                              hipStream_t stream) {
  const float* x = (const float*)d_in[0];   // [M+1]
  const float* m = (const float*)d_in[1];   // [M]
  const float* P = (const float*)d_in[2];   // [M*M]
  float* ws  = (float*)d_ws;
  float* out = (float*)d_out;

  k_init<<<dim3(M / TB), dim3(TB), 0, stream>>>(x, m, ws);
  for (int k = 0; k < MAXN; ++k) {
    k_stage<<<dim3(M / TB), dim3(TB), 0, stream>>>(m, ws, k);
    k_gemv <<<dim3(KC * (M / (TB * 4))), dim3(TB), 0, stream>>>(P, ws, k);
    k_epi  <<<dim3(M / TB), dim3(TB), 0, stream>>>(ws, k);
  }
  k_out<<<dim3((M + 1 + TB - 1) / TB), dim3(TB), 0, stream>>>(ws, out);
}